// Round 4
// baseline (1385.866 us; speedup 1.0000x reference)
//
#include <hip/hip_runtime.h>

typedef float v2f __attribute__((ext_vector_type(2)));
typedef _Float16 v2h __attribute__((ext_vector_type(2)));

#define LOG2E 1.4426950408889634f
#define LN2   0.6931471805599453f

__device__ __forceinline__ float fexp2(float x) {
  float r; asm("v_exp_f32 %0, %1" : "=v"(r) : "v"(x)); return r;
}
__device__ __forceinline__ float frcp(float x) {
  float r; asm("v_rcp_f32 %0, %1" : "=v"(r) : "v"(x)); return r;
}
__device__ __forceinline__ float flog2(float x) {
  float r; asm("v_log_f32 %0, %1" : "=v"(r) : "v"(x)); return r;
}
__device__ __forceinline__ v2h bch(float x) { return __builtin_bit_cast(v2h, x); }
// quad_perm lane swaps on the VALU pipe (no LDS traffic)
__device__ __forceinline__ float dpp_xor1(float v) {
  return __builtin_bit_cast(float,
      __builtin_amdgcn_update_dpp(0, __builtin_bit_cast(int, v), 0xB1, 0xF, 0xF, true));
}
__device__ __forceinline__ float dpp_xor2(float v) {
  return __builtin_bit_cast(float,
      __builtin_amdgcn_update_dpp(0, __builtin_bit_cast(int, v), 0x4E, 0xF, 0xF, true));
}
// LDS-ordering-only barrier: skips the vmcnt(0) drain __syncthreads would emit,
// so prefetched P-tiles / flush stores stay in flight across step barriers.
__device__ __forceinline__ void lgkm_barrier() {
  __builtin_amdgcn_sched_barrier(0);
  asm volatile("s_waitcnt lgkmcnt(0)" ::: "memory");
  __builtin_amdgcn_s_barrier();
  __builtin_amdgcn_sched_barrier(0);
}

// ---------------- embedding concat:  X[t][0..336) = [word(300) | pos(25) | 0pad] ----
__global__ void k_embed(const float* __restrict__ wv, const int* __restrict__ pidx,
                        const float* __restrict__ pemb, float* __restrict__ X) {
  int t = blockIdx.x;
  int pi = pidx[t];
  for (int c = threadIdx.x; c < 336; c += 128) {
    float v;
    if (c < 300)      v = wv[t * 300 + c];
    else if (c < 325) v = pemb[pi * 25 + (c - 300)];
    else              v = 0.f;
    X[t * 336 + c] = v;
  }
}

// ---------------- generic row repack with zero K-pad ------------------------------
__global__ void k_repack(const float* __restrict__ src, float* __restrict__ dst,
                         int sK, int dK) {
  int r = blockIdx.x;
  for (int c = threadIdx.x; c < dK; c += 128)
    dst[r * dK + c] = (c < sK) ? src[r * sK + c] : 0.f;
}

// ---------------- split fc1_W [100][500] -> Wab [200][256] ------------------------
__global__ void k_wab(const float* __restrict__ fc1W, float* __restrict__ Wab) {
  int r = blockIdx.x;                       // 0..199
  int sr = (r < 100) ? r : r - 100;
  int so = (r < 100) ? 0 : 250;
  for (int c = threadIdx.x; c < 256; c += 128)
    Wab[r * 256 + c] = (c < 250) ? fc1W[sr * 500 + so + c] : 0.f;
}

// ---------------- biasAB + sum(fc2_W) ----------------------------------------------
__global__ void k_misc(const float* __restrict__ fc1b, const float* __restrict__ fc2W,
                       float* __restrict__ biasAB, float* __restrict__ sumw) {
  __shared__ float red[128];
  int t = threadIdx.x;   // 128 threads
  for (int c = t; c < 256; c += 128)
    biasAB[c] = (c < 100) ? fc1b[c] : 0.f;
  float s = (t < 100) ? fc2W[t] : 0.f;
  red[t] = s; __syncthreads();
  for (int off = 64; off; off >>= 1) {
    if (t < off) red[t] += red[t + off];
    __syncthreads();
  }
  if (t == 0) sumw[0] = red[0];
}

// ---------------- tiled fp32 GEMM:  C = A @ B^T + bias -----------------------------
// A:[M][K], B:[N][K] (K mult of 16). transOut=0: C[m][n] (ldC=row len).
// transOut=1: C[n][m] (ldC = M), LDS-staged transpose for coalesced stores.
#define BM 64
#define BN 64
#define BKK 16
__global__ __launch_bounds__(256) void k_gemm(
    const float* __restrict__ A, const float* __restrict__ Bw,
    const float* __restrict__ bias, float* __restrict__ C,
    int M, int N, int K, int ldC, long sBz, long sCz, long sbz, int transOut) {
  const int z = blockIdx.z;
  const float* Bp = Bw + (size_t)z * sBz;
  const float* bp = bias + (size_t)z * sbz;
  float* Cp = C + (size_t)z * sCz;
  const int bm = blockIdx.y * BM, bn = blockIdx.x * BN;
  __shared__ __align__(16) float As[BKK][BM + 4];
  __shared__ __align__(16) float Bs[BKK][BN + 4];
  __shared__ float Ts[BN][BM + 1];
  const int tid = threadIdx.x;
  const int tx = tid & 15, ty = tid >> 4;
  const int lr = tid >> 2;            // 0..63
  const int lk = (tid & 3) * 4;       // 0,4,8,12
  float acc[4][4];
#pragma unroll
  for (int a = 0; a < 4; ++a)
#pragma unroll
    for (int b = 0; b < 4; ++b) acc[a][b] = 0.f;

  int brow = bn + lr; if (brow >= N) brow = N - 1;   // clamp (pad cols unused)
  for (int k0 = 0; k0 < K; k0 += BKK) {
    float4 a4 = *(const float4*)(A + (size_t)(bm + lr) * K + k0 + lk);
    float4 b4 = *(const float4*)(Bp + (size_t)brow * K + k0 + lk);
    __syncthreads();
    As[lk + 0][lr] = a4.x; As[lk + 1][lr] = a4.y; As[lk + 2][lr] = a4.z; As[lk + 3][lr] = a4.w;
    Bs[lk + 0][lr] = b4.x; Bs[lk + 1][lr] = b4.y; Bs[lk + 2][lr] = b4.z; Bs[lk + 3][lr] = b4.w;
    __syncthreads();
#pragma unroll
    for (int kk = 0; kk < BKK; ++kk) {
      float4 av = *(const float4*)&As[kk][ty * 4];
      float4 bv = *(const float4*)&Bs[kk][tx * 4];
      float aa[4] = {av.x, av.y, av.z, av.w};
      float bb[4] = {bv.x, bv.y, bv.z, bv.w};
#pragma unroll
      for (int a = 0; a < 4; ++a)
#pragma unroll
        for (int b = 0; b < 4; ++b)
          acc[a][b] = __builtin_fmaf(aa[a], bb[b], acc[a][b]);
    }
  }
  if (!transOut) {
#pragma unroll
    for (int a = 0; a < 4; ++a) {
      int i = bm + ty * 4 + a;
#pragma unroll
      for (int b = 0; b < 4; ++b) {
        int j = bn + tx * 4 + b;
        if (j < N) Cp[(size_t)i * ldC + j] = acc[a][b] + bp[j];
      }
    }
  } else {
    __syncthreads();
#pragma unroll
    for (int a = 0; a < 4; ++a)
#pragma unroll
      for (int b = 0; b < 4; ++b) {
        int jn = bn + tx * 4 + b; if (jn >= N) jn = N - 1;
        Ts[tx * 4 + b][ty * 4 + a] = acc[a][b] + bp[jn];
      }
    __syncthreads();
    const int n2 = tid >> 2, mq = (tid & 3) * 16;
    const int n = bn + n2;
    if (n < N) {
#pragma unroll
      for (int r = 0; r < 4; ++r) {
        int m0 = mq + r * 4;
        float4 v;
        v.x = Ts[n2][m0 + 0]; v.y = Ts[n2][m0 + 1];
        v.z = Ts[n2][m0 + 2]; v.w = Ts[n2][m0 + 3];
        *(float4*)(Cp + (size_t)n * ldC + bm + m0) = v;
      }
    }
  }
}

// ---------------- LSTM recurrence v4 (packed-f16 FMA matvec) ------------------------
// Pt: transposed pre-gates [d][500][1024] (row r = gate-row, col = time).
// Whh: [d][500][125]. hout: [1024][256] (d*125+u).
// 512 threads: t = 4*u + sub; thread owns rows {g*125+u} for g=0..3, cols sub*32..+31.
// Matvec via v_pk_fma_f16 (2 f16 MACs/lane/instr). If CDNA4 keeps the 2x packed-f16
// vector rate, this issues at 2 cyc/wave64 vs 4 for pk_fma_f32/dot2 -> matvec
// 512->256 cyc/SIMD/step. Accumulation: 8 v2h accumulators (2/gate, 8-deep chains),
// combined pk_add_f16 then f32. Pre-gates, DPP reduce, activations, c stay f32.
// (Round-3 evidence: v_dot2_f32_f16 issues at the f32 pk rate -> null; VALUBusy
// tracked instruction count, proving issue-bound. This is the remaining 2x lever.)
__global__ __launch_bounds__(512) void k_rec(const float* __restrict__ Pt,
                                             const float* __restrict__ Whh,
                                             float* __restrict__ hout) {
  const int d = blockIdx.x;
  const bool fwd = (d == 0);
  const int t = threadIdx.x;
  int u = t >> 2; const bool active = (u < 125); if (u > 124) u = 124;
  const int sub = t & 3;

  // ---- weights into VGPRs as packed f16 pairs: 4 gates x 16 v2h ----
  const float* Wd = Whh + (size_t)d * 500 * 125;
  v2h w16[4][16];
#pragma unroll
  for (int g = 0; g < 4; ++g) {
    const float* wr = Wd + (size_t)(g * 125 + u) * 125;
#pragma unroll
    for (int j = 0; j < 16; ++j) {
      int col = sub * 32 + 2 * j;
      v2h ww;
      ww.x = (_Float16)((col     < 125) ? wr[col]     : 0.f);
      ww.y = (_Float16)((col + 1 < 125) ? wr[col + 1] : 0.f);
      w16[g][j] = ww;
    }
  }

  // ---- LDS ----
  __shared__ __align__(16) _Float16 hh[2][128];  // h double-buffer, f16
  __shared__ float hist[32][128];                // h history (32 steps, f32) for hout
  for (int i = t; i < 128; i += 512) ((float*)hh)[i] = 0.f;  // 2*128 halves = 128 f32

  // ---- per-thread P^T column ----
  const int prow = sub * 125 + u;              // gate = sub
  const float4* Pr = (const float4*)(Pt + (size_t)d * 500 * 1024 + (size_t)prow * 1024);

  // activation constants: sub==2 is the g-gate (tanh); others sigmoid
  const float sM = (sub == 2) ? 2.f : 1.f;
  const float sA = (sub == 2) ? 2.f : 1.f;
  const float sB = (sub == 2) ? -1.f : 0.f;
  const bool m0s = (sub == 0), m1s = (sub == 1), m2s = (sub == 2);

  float cst = 0.f;
  // chunk 0 pre-gates
  float4 cura = Pr[fwd ? 0 : 254];
  float4 curb = Pr[fwd ? 1 : 255];
  __syncthreads();

  for (int cb = 0; cb < 128; ++cb) {
    // prefetch next chunk (stays in flight across lgkm-only barriers; compiler
    // inserts the counted vmcnt wait at the point of use)
    int nc = (cb + 1 < 128) ? cb + 1 : cb;
    float4 nxta = Pr[fwd ? 2 * nc     : 254 - 2 * nc];
    float4 nxtb = Pr[fwd ? 2 * nc + 1 : 255 - 2 * nc];
#pragma unroll
    for (int e = 0; e < 8; ++e) {
      const int buf = e & 1;
      // pre-gate for this step (element select folds at compile time)
      float pf = (e == 0) ? cura.x : (e == 1) ? cura.y : (e == 2) ? cura.z : (e == 3) ? cura.w
               : (e == 4) ? curb.x : (e == 5) ? curb.y : (e == 6) ? curb.z : curb.w;
      float pb = (e == 0) ? curb.w : (e == 1) ? curb.z : (e == 2) ? curb.y : (e == 3) ? curb.x
               : (e == 4) ? cura.w : (e == 5) ? cura.z : (e == 6) ? cura.y : cura.x;
      float pre = fwd ? pf : pb;
      // ---- matvec: 4 gate-rows x 32 cols, v_pk_fma_f16, 8 accumulators ----
      const float4* hp4 = (const float4*)&hh[buf][sub * 32];  // 64B = 4 x float4
      v2h z = {(_Float16)0.f, (_Float16)0.f};
      v2h c0a = z, c0b = z, c1a = z, c1b = z, c2a = z, c2b = z, c3a = z, c3b = z;
#pragma unroll
      for (int q4 = 0; q4 < 4; ++q4) {
        float4 hv4 = hp4[q4];
        v2h h0 = bch(hv4.x), h1 = bch(hv4.y), h2 = bch(hv4.z), h3 = bch(hv4.w);
        const int j0 = q4 * 4;
        c0a = __builtin_elementwise_fma(w16[0][j0 + 0], h0, c0a);
        c0b = __builtin_elementwise_fma(w16[0][j0 + 1], h1, c0b);
        c0a = __builtin_elementwise_fma(w16[0][j0 + 2], h2, c0a);
        c0b = __builtin_elementwise_fma(w16[0][j0 + 3], h3, c0b);
        c1a = __builtin_elementwise_fma(w16[1][j0 + 0], h0, c1a);
        c1b = __builtin_elementwise_fma(w16[1][j0 + 1], h1, c1b);
        c1a = __builtin_elementwise_fma(w16[1][j0 + 2], h2, c1a);
        c1b = __builtin_elementwise_fma(w16[1][j0 + 3], h3, c1b);
        c2a = __builtin_elementwise_fma(w16[2][j0 + 0], h0, c2a);
        c2b = __builtin_elementwise_fma(w16[2][j0 + 1], h1, c2b);
        c2a = __builtin_elementwise_fma(w16[2][j0 + 2], h2, c2a);
        c2b = __builtin_elementwise_fma(w16[2][j0 + 3], h3, c2b);
        c3a = __builtin_elementwise_fma(w16[3][j0 + 0], h0, c3a);
        c3b = __builtin_elementwise_fma(w16[3][j0 + 1], h1, c3b);
        c3a = __builtin_elementwise_fma(w16[3][j0 + 2], h2, c3a);
        c3b = __builtin_elementwise_fma(w16[3][j0 + 3], h3, c3b);
      }
      v2h s0 = c0a + c0b, s1 = c1a + c1b, s2 = c2a + c2b, s3 = c3a + c3b;
      float p0 = (float)s0.x + (float)s0.y;
      float p1 = (float)s1.x + (float)s1.y;
      float p2 = (float)s2.x + (float)s2.y;
      float p3 = (float)s3.x + (float)s3.y;
      // ---- reduce over the 4 sub-lanes (DPP quad butterflies) ----
      p0 += dpp_xor1(p0); p0 += dpp_xor2(p0);
      p1 += dpp_xor1(p1); p1 += dpp_xor2(p1);
      p2 += dpp_xor1(p2); p2 += dpp_xor2(p2);
      p3 += dpp_xor1(p3); p3 += dpp_xor2(p3);
      // each lane keeps its own gate (g == sub), adds pre-gate, activates
      float x = m0s ? p0 : m1s ? p1 : m2s ? p2 : p3;
      x += pre;
      float sg = frcp(1.f + fexp2(-LOG2E * (sM * x)));
      float a = __builtin_fmaf(sA, sg, sB);
      // ---- gather i,f,g,o into sub0 lane ----
      float fg = dpp_xor1(a);     // sub0: f
      float gg = dpp_xor2(a);     // sub0: g
      float og = dpp_xor2(fg);    // sub0: o
      cst = __builtin_fmaf(fg, cst, a * gg);
      float th = __builtin_fmaf(2.f, frcp(1.f + fexp2(-2.f * LOG2E * cst)), -1.f);
      float h = og * th;
      if (m0s && active) {
        hh[buf ^ 1][u] = (_Float16)h;
        hist[(cb & 3) * 8 + e][u] = h;
      }
      lgkm_barrier();
    }
    if ((cb & 3) == 3) {   // flush 32 steps of h to global
      const int S0 = (cb - 3) * 8;
#pragma unroll
      for (int k = 0; k < 8; ++k) {
        int idx = t + k * 512;
        int r = idx >> 7, u2 = idx & 127;
        if (u2 < 125) {
          int step = S0 + r;
          int time = fwd ? step : 1023 - step;
          hout[(size_t)time * 256 + d * 125 + u2] = hist[r][u2];
        }
      }
      lgkm_barrier();
    }
    cura = nxta; curb = nxtb;
  }
}

// ---------------- pairwise scorer ---------------------------------------------------
__global__ __launch_bounds__(256) void k_pair(const float* __restrict__ AB,
    const float* __restrict__ fc2W, const float* __restrict__ fc2b,
    const float* __restrict__ sumw, float* __restrict__ outS,
    float* __restrict__ scoresT) {
  __shared__ float As[32][100];
  __shared__ float Bs[32][101];
  __shared__ float w2s[100];
  const int tid = threadIdx.x;
  const int i0 = blockIdx.y * 32, j0 = blockIdx.x * 32;
  for (int idx = tid; idx < 3200; idx += 256) {
    int r = idx / 100, k = idx - r * 100;
    As[r][k] = AB[(size_t)(i0 + r) * 200 + k];
    Bs[r][k] = AB[(size_t)(j0 + r) * 200 + 100 + k];
  }
  if (tid < 100) w2s[tid] = 2.f * fc2W[tid];
  __syncthreads();
  const int tx = tid & 31, ty = tid >> 5;
  float acc[4] = {0.f, 0.f, 0.f, 0.f};
#pragma unroll 4
  for (int k = 0; k < 100; ++k) {
    float b = Bs[tx][k];
    float wk2 = w2s[k];
    float bs = b * (2.f * LOG2E);
#pragma unroll
    for (int q = 0; q < 4; ++q) {
      float a = As[ty + 8 * q][k];
      float r = frcp(1.f + fexp2(__builtin_fmaf(a, 2.f * LOG2E, bs)));
      acc[q] = __builtin_fmaf(wk2, r, acc[q]);
    }
  }
  float base = sumw[0] + fc2b[0];
  const int j = j0 + tx;
#pragma unroll
  for (int q = 0; q < 4; ++q) {
    int i = i0 + ty + 8 * q;
    float val = (i != j && j != 0) ? (base - acc[q]) : 0.f;
    outS[(size_t)i * 1024 + j] = val;
    scoresT[(size_t)j * 1024 + i] = val;
  }
}

// ---------------- per-child log-softmax contribution -------------------------------
__global__ __launch_bounds__(256) void k_soft(const float* __restrict__ scoresT,
    const int* __restrict__ parents, float* __restrict__ contrib) {
  const int j = blockIdx.x, tid = threadIdx.x;
  __shared__ float red[256];
  const float* row = scoresT + (size_t)j * 1024;
  float v0 = row[tid], v1 = row[tid + 256], v2 = row[tid + 512], v3 = row[tid + 768];
  float m = fmaxf(fmaxf(v0, v1), fmaxf(v2, v3));
  red[tid] = m; __syncthreads();
  for (int off = 128; off; off >>= 1) {
    if (tid < off) red[tid] = fmaxf(red[tid], red[tid + off]);
    __syncthreads();
  }
  m = red[0]; __syncthreads();
  float s = fexp2((v0 - m) * LOG2E) + fexp2((v1 - m) * LOG2E) +
            fexp2((v2 - m) * LOG2E) + fexp2((v3 - m) * LOG2E);
  red[tid] = s; __syncthreads();
  for (int off = 128; off; off >>= 1) {
    if (tid < off) red[tid] += red[tid + off];
    __syncthreads();
  }
  if (tid == 0) {
    float S = red[0];
    int p = parents[j];
    contrib[j] = row[p] - m - flog2(S) * LN2;
  }
}

__global__ __launch_bounds__(256) void k_loss(const float* __restrict__ contrib,
                                              float* __restrict__ out) {
  __shared__ float red[256];
  int tid = threadIdx.x;
  float s = contrib[tid] + contrib[tid + 256] + contrib[tid + 512] + contrib[tid + 768];
  red[tid] = s; __syncthreads();
  for (int off = 128; off; off >>= 1) {
    if (tid < off) red[tid] += red[tid + off];
    __syncthreads();
  }
  if (tid == 0) out[0] = -red[0] * (1.f / 1024.f);
}

// ---------------- launcher ---------------------------------------------------------
extern "C" void kernel_launch(void* const* d_in, const int* in_sizes, int n_in,
                              void* d_out, int out_size, void* d_ws, size_t ws_size,
                              hipStream_t stream) {
  const float* wv   = (const float*)d_in[0];
  const int*   pidx = (const int*)d_in[1];
  const int*   par  = (const int*)d_in[2];
  const float* pemb = (const float*)d_in[3];
  const float* Wih0 = (const float*)d_in[4];
  const float* Whh0 = (const float*)d_in[5];
  const float* b0   = (const float*)d_in[6];
  const float* Wih1 = (const float*)d_in[7];
  const float* Whh1 = (const float*)d_in[8];
  const float* b1   = (const float*)d_in[9];
  const float* fc1W = (const float*)d_in[10];
  const float* fc1b = (const float*)d_in[11];
  const float* fc2W = (const float*)d_in[12];
  const float* fc2b = (const float*)d_in[13];
  float* ws = (float*)d_ws;
  // workspace layout (float offsets)
  float* X      = ws + 0;        // 1024*336
  float* Wih0p  = ws + 344064;   // 2*500*336
  float* Pt0    = ws + 680064;   // 2*500*1024 (transposed pre-gates, layer 0)
  float* h0     = ws + 1704064;  // 1024*256
  float* Wih1p  = ws + 1966208;  // 2*500*256
  float* Pt1    = ws + 2222208;  // 2*500*1024 (transposed pre-gates, layer 1)
  float* h1     = ws + 3246208;  // 1024*256
  float* Wab    = ws + 3508352;  // 200*256
  float* biasAB = ws + 3559552;  // 256
  float* AB     = ws + 3559808;  // 1024*200
  float* scT    = ws + 3764608;  // 1024*1024
  float* contrib= ws + 4813184;  // 1024
  float* sumw   = ws + 4814208;  // 1
  float* out = (float*)d_out;

  // zero padded h buffers (cols 250..255 must stay 0 for the K=256 GEMMs)
  hipMemsetAsync(h0, 0, 1024 * 256 * sizeof(float), stream);
  hipMemsetAsync(h1, 0, 1024 * 256 * sizeof(float), stream);

  k_embed <<<1024, 128, 0, stream>>>(wv, pidx, pemb, X);
  k_repack<<<1000, 128, 0, stream>>>(Wih0, Wih0p, 325, 336);
  k_repack<<<1000, 128, 0, stream>>>(Wih1, Wih1p, 250, 256);
  k_wab   <<<200, 128, 0, stream>>>(fc1W, Wab);
  k_misc  <<<1, 128, 0, stream>>>(fc1b, fc2W, biasAB, sumw);

  // layer 0 (pre-gates stored transposed: Pt[z][n][m], ldC = 1024)
  k_gemm<<<dim3(8, 16, 2), 256, 0, stream>>>(X, Wih0p, b0, Pt0, 1024, 500, 336, 1024,
                                             500L * 336, 500L * 1024, 500L, 1);
  k_rec <<<2, 512, 0, stream>>>(Pt0, Whh0, h0);
  // layer 1
  k_gemm<<<dim3(8, 16, 2), 256, 0, stream>>>(h0, Wih1p, b1, Pt1, 1024, 500, 256, 1024,
                                             500L * 256, 500L * 1024, 500L, 1);
  k_rec <<<2, 512, 0, stream>>>(Pt1, Whh1, h1);
  // head/child projections (fc1_b folded into head half via biasAB)
  k_gemm<<<dim3(4, 16, 1), 256, 0, stream>>>(h1, Wab, biasAB, AB, 1024, 200, 256, 200,
                                             0L, 0L, 0L, 0);
  // pairwise scores + transposed copy
  k_pair<<<dim3(32, 32), 256, 0, stream>>>(AB, fc2W, fc2b, sumw, out + 1, scT);
  // per-child log-softmax and loss
  k_soft<<<1024, 256, 0, stream>>>(scT, par, contrib);
  k_loss<<<1, 256, 0, stream>>>(contrib, out);
}

// Round 5
// 1212.040 us; speedup vs baseline: 1.1434x; 1.1434x over previous
//
#include <hip/hip_runtime.h>

typedef float v2f __attribute__((ext_vector_type(2)));
typedef _Float16 f16x8 __attribute__((ext_vector_type(8)));
typedef float f32x4 __attribute__((ext_vector_type(4)));

#define LOG2E 1.4426950408889634f
#define LN2   0.6931471805599453f

__device__ __forceinline__ float fexp2(float x) {
  float r; asm("v_exp_f32 %0, %1" : "=v"(r) : "v"(x)); return r;
}
__device__ __forceinline__ float frcp(float x) {
  float r; asm("v_rcp_f32 %0, %1" : "=v"(r) : "v"(x)); return r;
}
__device__ __forceinline__ float flog2(float x) {
  float r; asm("v_log_f32 %0, %1" : "=v"(r) : "v"(x)); return r;
}
// LDS-ordering-only barrier: skips the vmcnt(0) drain __syncthreads would emit,
// so prefetched P-tiles / flush stores stay in flight across step barriers.
__device__ __forceinline__ void lgkm_barrier() {
  __builtin_amdgcn_sched_barrier(0);
  asm volatile("s_waitcnt lgkmcnt(0)" ::: "memory");
  __builtin_amdgcn_s_barrier();
  __builtin_amdgcn_sched_barrier(0);
}

// ---------------- embedding concat:  X[t][0..336) = [word(300) | pos(25) | 0pad] ----
__global__ void k_embed(const float* __restrict__ wv, const int* __restrict__ pidx,
                        const float* __restrict__ pemb, float* __restrict__ X) {
  int t = blockIdx.x;
  int pi = pidx[t];
  for (int c = threadIdx.x; c < 336; c += 128) {
    float v;
    if (c < 300)      v = wv[t * 300 + c];
    else if (c < 325) v = pemb[pi * 25 + (c - 300)];
    else              v = 0.f;
    X[t * 336 + c] = v;
  }
}

// ---------------- generic row repack with zero K-pad ------------------------------
__global__ void k_repack(const float* __restrict__ src, float* __restrict__ dst,
                         int sK, int dK) {
  int r = blockIdx.x;
  for (int c = threadIdx.x; c < dK; c += 128)
    dst[r * dK + c] = (c < sK) ? src[r * sK + c] : 0.f;
}

// ---------------- split fc1_W [100][500] -> Wab [200][256] ------------------------
__global__ void k_wab(const float* __restrict__ fc1W, float* __restrict__ Wab) {
  int r = blockIdx.x;                       // 0..199
  int sr = (r < 100) ? r : r - 100;
  int so = (r < 100) ? 0 : 250;
  for (int c = threadIdx.x; c < 256; c += 128)
    Wab[r * 256 + c] = (c < 250) ? fc1W[sr * 500 + so + c] : 0.f;
}

// ---------------- biasAB + sum(fc2_W) ----------------------------------------------
__global__ void k_misc(const float* __restrict__ fc1b, const float* __restrict__ fc2W,
                       float* __restrict__ biasAB, float* __restrict__ sumw) {
  __shared__ float red[128];
  int t = threadIdx.x;   // 128 threads
  for (int c = t; c < 256; c += 128)
    biasAB[c] = (c < 100) ? fc1b[c] : 0.f;
  float s = (t < 100) ? fc2W[t] : 0.f;
  red[t] = s; __syncthreads();
  for (int off = 64; off; off >>= 1) {
    if (t < off) red[t] += red[t + off];
    __syncthreads();
  }
  if (t == 0) sumw[0] = red[0];
}

// ---------------- tiled fp32 GEMM:  C = A @ B^T + bias -----------------------------
// A:[M][K], B:[N][K] (K mult of 16). transOut=0: C[m][n] (ldC=row len).
// transOut=1: C[n][m] (ldC = M), LDS-staged transpose for coalesced stores.
#define BM 64
#define BN 64
#define BKK 16
__global__ __launch_bounds__(256) void k_gemm(
    const float* __restrict__ A, const float* __restrict__ Bw,
    const float* __restrict__ bias, float* __restrict__ C,
    int M, int N, int K, int ldC, long sBz, long sCz, long sbz, int transOut) {
  const int z = blockIdx.z;
  const float* Bp = Bw + (size_t)z * sBz;
  const float* bp = bias + (size_t)z * sbz;
  float* Cp = C + (size_t)z * sCz;
  const int bm = blockIdx.y * BM, bn = blockIdx.x * BN;
  __shared__ __align__(16) float As[BKK][BM + 4];
  __shared__ __align__(16) float Bs[BKK][BN + 4];
  __shared__ float Ts[BN][BM + 1];
  const int tid = threadIdx.x;
  const int tx = tid & 15, ty = tid >> 4;
  const int lr = tid >> 2;            // 0..63
  const int lk = (tid & 3) * 4;       // 0,4,8,12
  float acc[4][4];
#pragma unroll
  for (int a = 0; a < 4; ++a)
#pragma unroll
    for (int b = 0; b < 4; ++b) acc[a][b] = 0.f;

  int brow = bn + lr; if (brow >= N) brow = N - 1;   // clamp (pad cols unused)
  for (int k0 = 0; k0 < K; k0 += BKK) {
    float4 a4 = *(const float4*)(A + (size_t)(bm + lr) * K + k0 + lk);
    float4 b4 = *(const float4*)(Bp + (size_t)brow * K + k0 + lk);
    __syncthreads();
    As[lk + 0][lr] = a4.x; As[lk + 1][lr] = a4.y; As[lk + 2][lr] = a4.z; As[lk + 3][lr] = a4.w;
    Bs[lk + 0][lr] = b4.x; Bs[lk + 1][lr] = b4.y; Bs[lk + 2][lr] = b4.z; Bs[lk + 3][lr] = b4.w;
    __syncthreads();
#pragma unroll
    for (int kk = 0; kk < BKK; ++kk) {
      float4 av = *(const float4*)&As[kk][ty * 4];
      float4 bv = *(const float4*)&Bs[kk][tx * 4];
      float aa[4] = {av.x, av.y, av.z, av.w};
      float bb[4] = {bv.x, bv.y, bv.z, bv.w};
#pragma unroll
      for (int a = 0; a < 4; ++a)
#pragma unroll
        for (int b = 0; b < 4; ++b)
          acc[a][b] = __builtin_fmaf(aa[a], bb[b], acc[a][b]);
    }
  }
  if (!transOut) {
#pragma unroll
    for (int a = 0; a < 4; ++a) {
      int i = bm + ty * 4 + a;
#pragma unroll
      for (int b = 0; b < 4; ++b) {
        int j = bn + tx * 4 + b;
        if (j < N) Cp[(size_t)i * ldC + j] = acc[a][b] + bp[j];
      }
    }
  } else {
    __syncthreads();
#pragma unroll
    for (int a = 0; a < 4; ++a)
#pragma unroll
      for (int b = 0; b < 4; ++b) {
        int jn = bn + tx * 4 + b; if (jn >= N) jn = N - 1;
        Ts[tx * 4 + b][ty * 4 + a] = acc[a][b] + bp[jn];
      }
    __syncthreads();
    const int n2 = tid >> 2, mq = (tid & 3) * 16;
    const int n = bn + n2;
    if (n < N) {
#pragma unroll
      for (int r = 0; r < 4; ++r) {
        int m0 = mq + r * 4;
        float4 v;
        v.x = Ts[n2][m0 + 0]; v.y = Ts[n2][m0 + 1];
        v.z = Ts[n2][m0 + 2]; v.w = Ts[n2][m0 + 3];
        *(float4*)(Cp + (size_t)n * ldC + bm + m0) = v;
      }
    }
  }
}

// ---------------- LSTM recurrence v5 (MFMA matvec) ---------------------------------
// Rounds 2-4 proved the step is VALU-issue-bound and ALL 2-MAC/lane vector ops
// (pk_fma_f32 / dot2_f32_f16 / pk_fma_f16) issue at the same 4-cyc rate: the
// 62.5k-MAC matvec has a 488 cyc/step vector-pipe floor. v5 moves it to the MFMA
// pipe: W repacked u-major (row rho = u*4+gate, padded 512x128 f16) as A-fragments
// held in regs; B = h broadcast to all 16 cols (f16 in LDS, slot-linear). Per step:
// 128 mfma_f32_16x16x32_f16 (16/wave, ~77 cyc on MFMA pipe). acc is initialized
// from the pre-gate LDS buffer (bias-add free). C/D layout (col=lane&15,
// row=(lane>>4)*4+reg) puts all 4 gates of one u in one lane's acc -> no DPP
// reduce; each lane selects tile q=(lane&15)>>2 and runs one full cell.
// A and B are packed with the SAME (lanegroup,elem)->k convention, so any
// hardware k-permutation cancels (A/B layouts are symmetric).
__global__ __launch_bounds__(512) void k_rec(const float* __restrict__ Pt,
                                             const float* __restrict__ Whh,
                                             float* __restrict__ hout) {
  const int d = blockIdx.x;
  const bool fwd = (d == 0);
  const int t = threadIdx.x;
  const int w  = t >> 6;      // wave 0..7
  const int l  = t & 63;
  const int lg = l >> 4;      // k-group selector; also u-offset in owned tile
  const int lc = l & 15;      // A-row within tile / D column (replica)
  const int q  = lc >> 2;     // owned row-tile after select

  // pre-gate column ownership (unchanged from legacy): thread t -> gate t&3, unit t>>2
  int u_p = t >> 2; const bool activep = (u_p < 125); if (u_p > 124) u_p = 124;
  const int sub = t & 3;
  const float4* Pr = (const float4*)(Pt + (size_t)d * 500 * 1024 +
                                     (size_t)(sub * 125 + u_p) * 1024);

  // ---- A fragments: a[rt][kt]; A-row = lc; rho = w*64+rt*16+lc; k = kt*32+lg*8+j --
  const float* Wd = Whh + (size_t)d * 500 * 125;
  f16x8 a[4][4];
#pragma unroll
  for (int rt = 0; rt < 4; ++rt) {
    const int rho = (w << 6) + (rt << 4) + lc;
    const int u2 = rho >> 2, g2 = rho & 3;
    const bool uok = (u2 < 125);
    const float* wr2 = Wd + (size_t)(g2 * 125 + (uok ? u2 : 0)) * 125;
#pragma unroll
    for (int kt = 0; kt < 4; ++kt) {
      f16x8 v;
#pragma unroll
      for (int j = 0; j < 8; ++j) {
        const int k = kt * 32 + lg * 8 + j;
        v[j] = (_Float16)((uok && k < 125) ? wr2[k] : 0.f);
      }
      a[rt][kt] = v;
    }
  }

  // ---- LDS ----
  __shared__ __align__(16) _Float16 hf[2][128];   // h f16, slot-linear in k
  __shared__ __align__(16) float preb[2][512];    // pre-gates, rho = u*4+g
  __shared__ float hist[32][128];                 // h history for batched hout flush
  for (int i = t; i < 128; i += 512) ((int*)hf)[i] = 0;
  for (int i = t; i < 1024; i += 512) ((float*)preb)[i] = 0.f;

  float4 cura = Pr[fwd ? 0 : 254];
  float4 curb = Pr[fwd ? 1 : 255];
  float cst = 0.f;
  if (activep) preb[0][t] = fwd ? cura.x : curb.w;   // pre for step 0
  __syncthreads();

  for (int cb = 0; cb < 128; ++cb) {
    // prefetch next chunk (stays in flight across lgkm-only barriers)
    const int nc = (cb + 1 < 128) ? cb + 1 : cb;
    float4 nxta = Pr[fwd ? 2 * nc     : 254 - 2 * nc];
    float4 nxtb = Pr[fwd ? 2 * nc + 1 : 255 - 2 * nc];
#pragma unroll
    for (int e = 0; e < 8; ++e) {
      const int buf = e & 1;
      // ---- B fragments: h broadcast (same slot convention as A) ----
      f16x8 hfr[4];
#pragma unroll
      for (int kt = 0; kt < 4; ++kt)
        hfr[kt] = *(const f16x8*)&hf[buf][kt * 32 + lg * 8];
      // ---- acc init = pre-gates (D rows (lg*4..+3) of each owned tile) ----
      f32x4 acc[4];
#pragma unroll
      for (int rt = 0; rt < 4; ++rt)
        acc[rt] = *(const f32x4*)&preb[buf][(w << 6) + (rt << 4) + (lg << 2)];
      // ---- 16 MFMAs, kt-outer so consecutive issues are independent ----
#pragma unroll
      for (int kt = 0; kt < 4; ++kt)
#pragma unroll
        for (int rt = 0; rt < 4; ++rt)
          acc[rt] = __builtin_amdgcn_mfma_f32_16x16x32_f16(a[rt][kt], hfr[kt],
                                                           acc[rt], 0, 0, 0);
      // ---- lane selects its owned tile; full cell in-lane (i,f,g,o = regs 0..3) --
      f32x4 T = (q == 0) ? acc[0] : (q == 1) ? acc[1] : (q == 2) ? acc[2] : acc[3];
      float gi = frcp(1.f + fexp2(-LOG2E * T[0]));
      float gf = frcp(1.f + fexp2(-LOG2E * T[1]));
      float gg = __builtin_fmaf(2.f, frcp(1.f + fexp2(-2.f * LOG2E * T[2])), -1.f);
      float go = frcp(1.f + fexp2(-LOG2E * T[3]));
      cst = __builtin_fmaf(gf, cst, gi * gg);
      float th = __builtin_fmaf(2.f, frcp(1.f + fexp2(-2.f * LOG2E * cst)), -1.f);
      float hv = go * th;
      // ---- pre-gate for step e+1 (written into the other buffer) ----
      float pf, pb2;
      if (e < 7) {
        pf  = (e == 0) ? cura.y : (e == 1) ? cura.z : (e == 2) ? cura.w
            : (e == 3) ? curb.x : (e == 4) ? curb.y : (e == 5) ? curb.z : curb.w;
        pb2 = (e == 0) ? curb.z : (e == 1) ? curb.y : (e == 2) ? curb.x
            : (e == 3) ? cura.w : (e == 4) ? cura.z : (e == 5) ? cura.y : cura.x;
      } else { pf = nxta.x; pb2 = nxtb.w; }
      const float pre_next = fwd ? pf : pb2;
      // ---- writers: one replica lane per cell ----
      const int u_own = (w << 4) + (q << 2) + lg;
      if (((lc & 3) == 0) && u_own < 125) {
        hf[buf ^ 1][u_own] = (_Float16)hv;
        hist[(cb & 3) * 8 + e][u_own] = hv;
      }
      if (activep) preb[buf ^ 1][t] = pre_next;
      lgkm_barrier();
    }
    if ((cb & 3) == 3) {   // flush 32 steps of h to global
      const int S0 = (cb - 3) * 8;
#pragma unroll
      for (int k = 0; k < 8; ++k) {
        int idx = t + k * 512;
        int r = idx >> 7, u2 = idx & 127;
        if (u2 < 125) {
          int step = S0 + r;
          int time = fwd ? step : 1023 - step;
          hout[(size_t)time * 256 + d * 125 + u2] = hist[r][u2];
        }
      }
      lgkm_barrier();
    }
    cura = nxta; curb = nxtb;
  }
}

// ---------------- pairwise scorer ---------------------------------------------------
__global__ __launch_bounds__(256) void k_pair(const float* __restrict__ AB,
    const float* __restrict__ fc2W, const float* __restrict__ fc2b,
    const float* __restrict__ sumw, float* __restrict__ outS,
    float* __restrict__ scoresT) {
  __shared__ float As[32][100];
  __shared__ float Bs[32][101];
  __shared__ float w2s[100];
  const int tid = threadIdx.x;
  const int i0 = blockIdx.y * 32, j0 = blockIdx.x * 32;
  for (int idx = tid; idx < 3200; idx += 256) {
    int r = idx / 100, k = idx - r * 100;
    As[r][k] = AB[(size_t)(i0 + r) * 200 + k];
    Bs[r][k] = AB[(size_t)(j0 + r) * 200 + 100 + k];
  }
  if (tid < 100) w2s[tid] = 2.f * fc2W[tid];
  __syncthreads();
  const int tx = tid & 31, ty = tid >> 5;
  float acc[4] = {0.f, 0.f, 0.f, 0.f};
#pragma unroll 4
  for (int k = 0; k < 100; ++k) {
    float b = Bs[tx][k];
    float wk2 = w2s[k];
    float bs = b * (2.f * LOG2E);
#pragma unroll
    for (int q = 0; q < 4; ++q) {
      float a = As[ty + 8 * q][k];
      float r = frcp(1.f + fexp2(__builtin_fmaf(a, 2.f * LOG2E, bs)));
      acc[q] = __builtin_fmaf(wk2, r, acc[q]);
    }
  }
  float base = sumw[0] + fc2b[0];
  const int j = j0 + tx;
#pragma unroll
  for (int q = 0; q < 4; ++q) {
    int i = i0 + ty + 8 * q;
    float val = (i != j && j != 0) ? (base - acc[q]) : 0.f;
    outS[(size_t)i * 1024 + j] = val;
    scoresT[(size_t)j * 1024 + i] = val;
  }
}

// ---------------- per-child log-softmax contribution -------------------------------
__global__ __launch_bounds__(256) void k_soft(const float* __restrict__ scoresT,
    const int* __restrict__ parents, float* __restrict__ contrib) {
  const int j = blockIdx.x, tid = threadIdx.x;
  __shared__ float red[256];
  const float* row = scoresT + (size_t)j * 1024;
  float v0 = row[tid], v1 = row[tid + 256], v2 = row[tid + 512], v3 = row[tid + 768];
  float m = fmaxf(fmaxf(v0, v1), fmaxf(v2, v3));
  red[tid] = m; __syncthreads();
  for (int off = 128; off; off >>= 1) {
    if (tid < off) red[tid] = fmaxf(red[tid], red[tid + off]);
    __syncthreads();
  }
  m = red[0]; __syncthreads();
  float s = fexp2((v0 - m) * LOG2E) + fexp2((v1 - m) * LOG2E) +
            fexp2((v2 - m) * LOG2E) + fexp2((v3 - m) * LOG2E);
  red[tid] = s; __syncthreads();
  for (int off = 128; off; off >>= 1) {
    if (tid < off) red[tid] += red[tid + off];
    __syncthreads();
  }
  if (tid == 0) {
    float S = red[0];
    int p = parents[j];
    contrib[j] = row[p] - m - flog2(S) * LN2;
  }
}

__global__ __launch_bounds__(256) void k_loss(const float* __restrict__ contrib,
                                              float* __restrict__ out) {
  __shared__ float red[256];
  int tid = threadIdx.x;
  float s = contrib[tid] + contrib[tid + 256] + contrib[tid + 512] + contrib[tid + 768];
  red[tid] = s; __syncthreads();
  for (int off = 128; off; off >>= 1) {
    if (tid < off) red[tid] += red[tid + off];
    __syncthreads();
  }
  if (tid == 0) out[0] = -red[0] * (1.f / 1024.f);
}

// ---------------- launcher ---------------------------------------------------------
extern "C" void kernel_launch(void* const* d_in, const int* in_sizes, int n_in,
                              void* d_out, int out_size, void* d_ws, size_t ws_size,
                              hipStream_t stream) {
  const float* wv   = (const float*)d_in[0];
  const int*   pidx = (const int*)d_in[1];
  const int*   par  = (const int*)d_in[2];
  const float* pemb = (const float*)d_in[3];
  const float* Wih0 = (const float*)d_in[4];
  const float* Whh0 = (const float*)d_in[5];
  const float* b0   = (const float*)d_in[6];
  const float* Wih1 = (const float*)d_in[7];
  const float* Whh1 = (const float*)d_in[8];
  const float* b1   = (const float*)d_in[9];
  const float* fc1W = (const float*)d_in[10];
  const float* fc1b = (const float*)d_in[11];
  const float* fc2W = (const float*)d_in[12];
  const float* fc2b = (const float*)d_in[13];
  float* ws = (float*)d_ws;
  // workspace layout (float offsets)
  float* X      = ws + 0;        // 1024*336
  float* Wih0p  = ws + 344064;   // 2*500*336
  float* Pt0    = ws + 680064;   // 2*500*1024 (transposed pre-gates, layer 0)
  float* h0     = ws + 1704064;  // 1024*256
  float* Wih1p  = ws + 1966208;  // 2*500*256
  float* Pt1    = ws + 2222208;  // 2*500*1024 (transposed pre-gates, layer 1)
  float* h1     = ws + 3246208;  // 1024*256
  float* Wab    = ws + 3508352;  // 200*256
  float* biasAB = ws + 3559552;  // 256
  float* AB     = ws + 3559808;  // 1024*200
  float* scT    = ws + 3764608;  // 1024*1024
  float* contrib= ws + 4813184;  // 1024
  float* sumw   = ws + 4814208;  // 1
  float* out = (float*)d_out;

  // zero padded h buffers (cols 250..255 must stay 0 for the K=256 GEMMs)
  hipMemsetAsync(h0, 0, 1024 * 256 * sizeof(float), stream);
  hipMemsetAsync(h1, 0, 1024 * 256 * sizeof(float), stream);

  k_embed <<<1024, 128, 0, stream>>>(wv, pidx, pemb, X);
  k_repack<<<1000, 128, 0, stream>>>(Wih0, Wih0p, 325, 336);
  k_repack<<<1000, 128, 0, stream>>>(Wih1, Wih1p, 250, 256);
  k_wab   <<<200, 128, 0, stream>>>(fc1W, Wab);
  k_misc  <<<1, 128, 0, stream>>>(fc1b, fc2W, biasAB, sumw);

  // layer 0 (pre-gates stored transposed: Pt[z][n][m], ldC = 1024)
  k_gemm<<<dim3(8, 16, 2), 256, 0, stream>>>(X, Wih0p, b0, Pt0, 1024, 500, 336, 1024,
                                             500L * 336, 500L * 1024, 500L, 1);
  k_rec <<<2, 512, 0, stream>>>(Pt0, Whh0, h0);
  // layer 1
  k_gemm<<<dim3(8, 16, 2), 256, 0, stream>>>(h0, Wih1p, b1, Pt1, 1024, 500, 256, 1024,
                                             500L * 256, 500L * 1024, 500L, 1);
  k_rec <<<2, 512, 0, stream>>>(Pt1, Whh1, h1);
  // head/child projections (fc1_b folded into head half via biasAB)
  k_gemm<<<dim3(4, 16, 1), 256, 0, stream>>>(h1, Wab, biasAB, AB, 1024, 200, 256, 200,
                                             0L, 0L, 0L, 0);
  // pairwise scores + transposed copy
  k_pair<<<dim3(32, 32), 256, 0, stream>>>(AB, fc2W, fc2b, sumw, out + 1, scT);
  // per-child log-softmax and loss
  k_soft<<<1024, 256, 0, stream>>>(scT, par, contrib);
  k_loss<<<1, 256, 0, stream>>>(contrib, out);
}